// Round 6
// baseline (288.131 us; speedup 1.0000x reference)
//
#include <hip/hip_runtime.h>

constexpr int NN = 50000;   // nodes
constexpr int NE = 600000;  // edges
constexpr int D  = 128;     // features
constexpr int NR = 8;       // relations

constexpr int SCAN_ELEMS = 1024;
constexpr int NBLK_SCAN  = (NN + SCAN_ELEMS - 1) / SCAN_ELEMS;   // 49

typedef unsigned int   u32;
typedef unsigned short u16;
typedef float  f32x4 __attribute__((ext_vector_type(4)));
typedef short  s16x8 __attribute__((ext_vector_type(8)));

__device__ __forceinline__ u16 f2bf(float f) {
    u32 u = __float_as_uint(f);
    u32 r = (u + 0x7fffu + ((u >> 16) & 1u)) >> 16;   // RNE
    return (u16)r;
}

// ---------------- phase 1: per-dst edge counts ---------------------------
__global__ __launch_bounds__(256) void count_dst(const int* __restrict__ dst,
                                                 int* __restrict__ cnt_d) {
    int e = blockIdx.x * 256 + threadIdx.x;
    if (e < NE) atomicAdd(&cnt_d[dst[e]], 1);
}

// ---------------- phase 2: exclusive scan of cnt_d -> offs ---------------
__global__ __launch_bounds__(256) void scan1(const int* __restrict__ cnt,
                                             int* __restrict__ offs,
                                             int* __restrict__ bsums) {
    __shared__ int lds[256];
    int t = threadIdx.x;
    int base = blockIdx.x * SCAN_ELEMS + t * 4;
    int v0 = (base + 0 < NN) ? cnt[base + 0] : 0;
    int v1 = (base + 1 < NN) ? cnt[base + 1] : 0;
    int v2 = (base + 2 < NN) ? cnt[base + 2] : 0;
    int v3 = (base + 3 < NN) ? cnt[base + 3] : 0;
    int s = v0 + v1 + v2 + v3;
    lds[t] = s;
    __syncthreads();
    int val = s;
    for (int off = 1; off < 256; off <<= 1) {
        int tmp = (t >= off) ? lds[t - off] : 0;
        __syncthreads();
        val += tmp;
        lds[t] = val;
        __syncthreads();
    }
    int ex = val - s;
    if (base + 0 < NN) offs[base + 0] = ex;
    if (base + 1 < NN) offs[base + 1] = ex + v0;
    if (base + 2 < NN) offs[base + 2] = ex + v0 + v1;
    if (base + 3 < NN) offs[base + 3] = ex + v0 + v1 + v2;
    if (t == 255) bsums[blockIdx.x] = val;
}

__global__ __launch_bounds__(64) void scan2(int* __restrict__ bsums) {
    __shared__ int lds[64];
    int t = threadIdx.x;
    int v = (t < NBLK_SCAN) ? bsums[t] : 0;
    lds[t] = v;
    __syncthreads();
    int val = v;
    for (int off = 1; off < 64; off <<= 1) {
        int tmp = (t >= off) ? lds[t - off] : 0;
        __syncthreads();
        val += tmp;
        lds[t] = val;
        __syncthreads();
    }
    if (t < NBLK_SCAN) bsums[t] = val - v;
}

__global__ __launch_bounds__(256) void scan3(int* __restrict__ offs,
                                             const int* __restrict__ bsums) {
    int i = blockIdx.x * 256 + threadIdx.x;
    if (i < NN) offs[i] += bsums[i >> 10];
    if (i == 0) offs[NN] = NE;
}

// ---------------- phase 3: bin edges by dst ------------------------------
__global__ __launch_bounds__(256) void fill_bins(const int* __restrict__ src,
                                                 const int* __restrict__ dst,
                                                 const int* __restrict__ et,
                                                 const int* __restrict__ offs,
                                                 int* __restrict__ cur,
                                                 int* __restrict__ ebin) {
    int e = blockIdx.x * 256 + threadIdx.x;
    if (e >= NE) return;
    int d = dst[e];
    int idx = offs[d] + atomicAdd(&cur[d], 1);
    ebin[idx] = (et[e] << 16) | src[e];   // src < 50000 < 2^16
}

// ---------------- prep: x -> bf16, W/root -> bf16 transposed [c][k] ------
__global__ __launch_bounds__(256) void prep_kernel(const float* __restrict__ x,
                                                   const float* __restrict__ weight,
                                                   const float* __restrict__ root,
                                                   u16* __restrict__ xb,
                                                   u16* __restrict__ wt,
                                                   u16* __restrict__ rt) {
    const int NX4 = NN * D / 4;   // 1.6M float4 groups
    int gid = blockIdx.x * 256 + threadIdx.x;
    if (gid < NX4) {
        int i = gid * 4;
        float4 v = *(const float4*)(x + i);
        ushort4 o;
        o.x = f2bf(v.x); o.y = f2bf(v.y); o.z = f2bf(v.z); o.w = f2bf(v.w);
        *(ushort4*)(xb + i) = o;
        return;
    }
    int g = gid - NX4;
    if (g >= (NR + 1) * D * D) return;
    int p = g >> 14;              // plane 0..8
    int idx = g & 16383;          // c*128 + k
    int c = idx >> 7, k = idx & 127;
    float v = (p < NR) ? weight[(size_t)p * D * D + k * D + c] : root[k * D + c];
    u16* dst = (p < NR) ? (wt + (size_t)p * D * D) : rt;
    dst[idx] = f2bf(v);
}

// ---------------- phase 4: Y_r = x @ W_r (r<8) ; out = x @ root (r=8) ----
// LDS-free MFMA GEMM, K=128 single-shot. Block = 128 rows x 128 cols of one
// plane; 4 waves, each 32 rows x 128 cols = 2x8 tiles of 16x16x32 (16 MFMA).
// A/B fragments loaded straight from global (xb is 12.8MB L3-resident; the
// 32KB W-plane is L2-hot across all 391 row-blocks). No barriers, no LDS.
// Y packed per-lane: Y32[r][n][j] = bf16 cols {j, j+64}  (j = 0..63).
__global__ __launch_bounds__(256) void gemm9(const u16* __restrict__ xb,
                                             const u16* __restrict__ wt,
                                             const u16* __restrict__ rt,
                                             u32* __restrict__ Y32,
                                             float* __restrict__ out) {
    const int p    = blockIdx.x;          // plane 0..8 (8 = root)
    const int m0   = blockIdx.y * 128;
    const int wave = threadIdx.x >> 6;
    const int lane = threadIdx.x & 63;
    const int wm   = wave * 32;
    const int fr   = lane & 15;           // frag row/col within 16
    const int fq   = lane >> 4;           // 0..3
    const u16* B = (p < NR) ? wt + (size_t)p * D * D : rt;

    f32x4 acc[2][8];
#pragma unroll
    for (int i = 0; i < 2; ++i)
#pragma unroll
        for (int j = 0; j < 8; ++j) acc[i][j] = (f32x4){0.f, 0.f, 0.f, 0.f};

#pragma unroll
    for (int kk = 0; kk < 4; ++kk) {
        const int ko = kk * 32 + fq * 8;   // this lane's k-base
        s16x8 af[2], bfr[8];
#pragma unroll
        for (int mt = 0; mt < 2; ++mt) {
            int row = m0 + wm + mt * 16 + fr;
            if (row > NN - 1) row = NN - 1;            // tail clamp
            af[mt] = *(const s16x8*)(xb + (size_t)row * D + ko);
        }
#pragma unroll
        for (int nt = 0; nt < 8; ++nt)
            bfr[nt] = *(const s16x8*)(B + (nt * 16 + fr) * D + ko);
#pragma unroll
        for (int mt = 0; mt < 2; ++mt)
#pragma unroll
            for (int nt = 0; nt < 8; ++nt)
                acc[mt][nt] = __builtin_amdgcn_mfma_f32_16x16x32_bf16(
                    af[mt], bfr[nt], acc[mt][nt], 0, 0, 0);
    }

    // C/D: col = tile*16 + fr-part (lane&15), row = fq*4 + reg
    if (p < NR) {
        u32* Yp = Y32 + (size_t)p * NN * 64;
#pragma unroll
        for (int mt = 0; mt < 2; ++mt)
#pragma unroll
            for (int reg = 0; reg < 4; ++reg) {
                int n = m0 + wm + mt * 16 + fq * 4 + reg;
                if (n >= NN) continue;
#pragma unroll
                for (int nt = 0; nt < 4; ++nt) {
                    u32 lo = f2bf(acc[mt][nt][reg]);          // col nt*16+fr
                    u32 hi = f2bf(acc[mt][nt + 4][reg]);      // col nt*16+fr+64
                    Yp[(size_t)n * 64 + nt * 16 + fr] = lo | (hi << 16);
                }
            }
    } else {
#pragma unroll
        for (int mt = 0; mt < 2; ++mt)
#pragma unroll
            for (int reg = 0; reg < 4; ++reg) {
                int n = m0 + wm + mt * 16 + fq * 4 + reg;
                if (n >= NN) continue;
#pragma unroll
                for (int nt = 0; nt < 8; ++nt)
                    out[(size_t)n * D + nt * 16 + fr] = acc[mt][nt][reg];
            }
    }
}

// ---------------- phase 5: aggregate means into out (fused bias+relu) ----
// One wave per node. ebin[beg+lane] loaded once per 64-edge chunk; scalar
// readlane iteration. Pass 1 counts relations (scalar), pass 2 gathers
// Y rows scaled by inv_cnt[rel] into ONE fp32 pair per lane (cols lane,
// lane+64), then out = relu(root_part + agg + bias).
__global__ __launch_bounds__(128) void aggregate2(const u32* __restrict__ Y32,
                                                  const int* __restrict__ offs,
                                                  const int* __restrict__ ebin,
                                                  const float* __restrict__ bias,
                                                  float* __restrict__ out) {
    const int lane = threadIdx.x & 63;
    const int n = blockIdx.x * 2 + (threadIdx.x >> 6);
    if (n >= NN) return;
    const int beg = __builtin_amdgcn_readfirstlane(offs[n]);
    const int end = __builtin_amdgcn_readfirstlane(offs[n + 1]);

    int c0 = 0, c1 = 0, c2 = 0, c3 = 0, c4 = 0, c5 = 0, c6 = 0, c7 = 0;
    for (int b = beg; b < end; b += 64) {
        int rem = end - b;
        int lim = rem < 64 ? rem : 64;
        int epk = (lane < lim) ? ebin[b + lane] : 0;
        for (int j = 0; j < lim; ++j) {
            int pk = __builtin_amdgcn_readlane(epk, j);
            switch ((u32)pk >> 16) {
            case 0: ++c0; break; case 1: ++c1; break;
            case 2: ++c2; break; case 3: ++c3; break;
            case 4: ++c4; break; case 5: ++c5; break;
            case 6: ++c6; break; default: ++c7; break;
            }
        }
    }
    const float i0 = 1.0f / (float)(c0 > 0 ? c0 : 1);
    const float i1 = 1.0f / (float)(c1 > 0 ? c1 : 1);
    const float i2 = 1.0f / (float)(c2 > 0 ? c2 : 1);
    const float i3 = 1.0f / (float)(c3 > 0 ? c3 : 1);
    const float i4 = 1.0f / (float)(c4 > 0 ? c4 : 1);
    const float i5 = 1.0f / (float)(c5 > 0 ? c5 : 1);
    const float i6 = 1.0f / (float)(c6 > 0 ? c6 : 1);
    const float i7 = 1.0f / (float)(c7 > 0 ? c7 : 1);

    float alo = 0.f, ahi = 0.f;

#define BODY(PK, V)                                                          \
    {                                                                        \
        float lo_ = __uint_as_float((V) << 16);                              \
        float hi_ = __uint_as_float((V) & 0xffff0000u);                      \
        float sc_;                                                           \
        switch ((u32)(PK) >> 16) {                                           \
        case 0: sc_ = i0; break; case 1: sc_ = i1; break;                    \
        case 2: sc_ = i2; break; case 3: sc_ = i3; break;                    \
        case 4: sc_ = i4; break; case 5: sc_ = i5; break;                    \
        case 6: sc_ = i6; break; default: sc_ = i7; break;                   \
        }                                                                    \
        alo = fmaf(sc_, lo_, alo);                                           \
        ahi = fmaf(sc_, hi_, ahi);                                           \
    }

    for (int b = beg; b < end; b += 64) {
        int rem = end - b;
        int lim = rem < 64 ? rem : 64;
        int epk = (lane < lim) ? ebin[b + lane] : 0;
        int j = 0;
        for (; j + 4 <= lim; j += 4) {
            int pk0 = __builtin_amdgcn_readlane(epk, j + 0);
            int pk1 = __builtin_amdgcn_readlane(epk, j + 1);
            int pk2 = __builtin_amdgcn_readlane(epk, j + 2);
            int pk3 = __builtin_amdgcn_readlane(epk, j + 3);
            u32 v0 = Y32[(size_t)(((u32)pk0 >> 16) * NN + (pk0 & 0xffff)) * 64 + lane];
            u32 v1 = Y32[(size_t)(((u32)pk1 >> 16) * NN + (pk1 & 0xffff)) * 64 + lane];
            u32 v2 = Y32[(size_t)(((u32)pk2 >> 16) * NN + (pk2 & 0xffff)) * 64 + lane];
            u32 v3 = Y32[(size_t)(((u32)pk3 >> 16) * NN + (pk3 & 0xffff)) * 64 + lane];
            BODY(pk0, v0) BODY(pk1, v1) BODY(pk2, v2) BODY(pk3, v3)
        }
        for (; j < lim; ++j) {
            int pk = __builtin_amdgcn_readlane(epk, j);
            u32 v = Y32[(size_t)(((u32)pk >> 16) * NN + (pk & 0xffff)) * 64 + lane];
            BODY(pk, v)
        }
    }
#undef BODY

    float o0 = out[(size_t)n * D + lane] + alo + bias[lane];
    float o1 = out[(size_t)n * D + 64 + lane] + ahi + bias[64 + lane];
    out[(size_t)n * D + lane]      = fmaxf(o0, 0.f);
    out[(size_t)n * D + 64 + lane] = fmaxf(o1, 0.f);
}

extern "C" void kernel_launch(void* const* d_in, const int* in_sizes, int n_in,
                              void* d_out, int out_size, void* d_ws, size_t ws_size,
                              hipStream_t stream) {
    const float* x      = (const float*)d_in[0];
    const int*   ei     = (const int*)d_in[1];
    const int*   et     = (const int*)d_in[2];
    const float* weight = (const float*)d_in[3];
    const float* root   = (const float*)d_in[4];
    const float* bias   = (const float*)d_in[5];
    float* out = (float*)d_out;
    const int* srcv = ei;
    const int* dstv = ei + NE;

    // ws: ints [cnt_d NN][cur NN][offs NN+1][bsums 64][ebin NE],
    // then u16 [xb NN*D][wt NR*D*D][rt D*D], then u32 [Y32 NR*NN*64] (~118 MB)
    int* cnt_d = (int*)d_ws;
    int* cur   = cnt_d + NN;
    int* offs  = cur + NN;
    int* bsums = offs + NN + 1;
    int* ebin  = bsums + 64;
    size_t fixed_b  = ((char*)(ebin + NE) - (char*)d_ws);
    size_t fixed_al = (fixed_b + 255) & ~(size_t)255;
    u16* xb  = (u16*)((char*)d_ws + fixed_al);
    u16* wt  = xb + (size_t)NN * D;
    u16* rt  = wt + (size_t)NR * D * D;
    u32* Y32 = (u32*)(rt + (size_t)D * D);

    hipMemsetAsync(cnt_d, 0, 2 * NN * sizeof(int), stream);
    count_dst<<<(NE + 255) / 256, 256, 0, stream>>>(dstv, cnt_d);
    scan1<<<NBLK_SCAN, 256, 0, stream>>>(cnt_d, offs, bsums);
    scan2<<<1, 64, 0, stream>>>(bsums);
    scan3<<<(NN + 255) / 256, 256, 0, stream>>>(offs, bsums);
    fill_bins<<<(NE + 255) / 256, 256, 0, stream>>>(srcv, dstv, et, offs, cur, ebin);

    const int PREP = NN * D / 4 + (NR + 1) * D * D;
    prep_kernel<<<(PREP + 255) / 256, 256, 0, stream>>>(x, weight, root, xb, wt, rt);

    dim3 ggrid(NR + 1, (NN + 127) / 128);   // plane fastest -> A-tile L2 reuse
    gemm9<<<ggrid, 256, 0, stream>>>(xb, wt, rt, Y32, out);

    aggregate2<<<(NN + 1) / 2, 128, 0, stream>>>(Y32, offs, ebin, bias, out);
}

// Round 7
// 266.866 us; speedup vs baseline: 1.0797x; 1.0797x over previous
//
#include <hip/hip_runtime.h>

constexpr int NN = 50000;   // nodes
constexpr int NE = 600000;  // edges
constexpr int D  = 128;     // features
constexpr int NR = 8;       // relations
constexpr int KT = (NR + 1) * D;   // 1152 total K (root plane + 8 relation planes)

constexpr int SCAN_ELEMS = 1024;
constexpr int NBLK_SCAN  = (NN + SCAN_ELEMS - 1) / SCAN_ELEMS;   // 49

typedef unsigned int   u32;
typedef unsigned short u16;
typedef float  f32x4 __attribute__((ext_vector_type(4)));
typedef short  s16x8 __attribute__((ext_vector_type(8)));

__device__ __forceinline__ u16 f2bf(float f) {
    u32 u = __float_as_uint(f);
    u32 r = (u + 0x7fffu + ((u >> 16) & 1u)) >> 16;   // RNE
    return (u16)r;
}

__device__ __forceinline__ void async_cp16(const void* g, void* l) {
    __builtin_amdgcn_global_load_lds(
        (const __attribute__((address_space(1))) u32*)g,
        (__attribute__((address_space(3))) u32*)l, 16, 0, 0);
}

// ---------------- phase 1: per-dst edge counts ---------------------------
__global__ __launch_bounds__(256) void count_dst(const int* __restrict__ dst,
                                                 int* __restrict__ cnt_d) {
    int e = blockIdx.x * 256 + threadIdx.x;
    if (e < NE) atomicAdd(&cnt_d[dst[e]], 1);
}

// ---------------- phase 2: exclusive scan of cnt_d -> offs ---------------
__global__ __launch_bounds__(256) void scan1(const int* __restrict__ cnt,
                                             int* __restrict__ offs,
                                             int* __restrict__ bsums) {
    __shared__ int lds[256];
    int t = threadIdx.x;
    int base = blockIdx.x * SCAN_ELEMS + t * 4;
    int v0 = (base + 0 < NN) ? cnt[base + 0] : 0;
    int v1 = (base + 1 < NN) ? cnt[base + 1] : 0;
    int v2 = (base + 2 < NN) ? cnt[base + 2] : 0;
    int v3 = (base + 3 < NN) ? cnt[base + 3] : 0;
    int s = v0 + v1 + v2 + v3;
    lds[t] = s;
    __syncthreads();
    int val = s;
    for (int off = 1; off < 256; off <<= 1) {
        int tmp = (t >= off) ? lds[t - off] : 0;
        __syncthreads();
        val += tmp;
        lds[t] = val;
        __syncthreads();
    }
    int ex = val - s;
    if (base + 0 < NN) offs[base + 0] = ex;
    if (base + 1 < NN) offs[base + 1] = ex + v0;
    if (base + 2 < NN) offs[base + 2] = ex + v0 + v1;
    if (base + 3 < NN) offs[base + 3] = ex + v0 + v1 + v2;
    if (t == 255) bsums[blockIdx.x] = val;
}

__global__ __launch_bounds__(64) void scan2(int* __restrict__ bsums) {
    __shared__ int lds[64];
    int t = threadIdx.x;
    int v = (t < NBLK_SCAN) ? bsums[t] : 0;
    lds[t] = v;
    __syncthreads();
    int val = v;
    for (int off = 1; off < 64; off <<= 1) {
        int tmp = (t >= off) ? lds[t - off] : 0;
        __syncthreads();
        val += tmp;
        lds[t] = val;
        __syncthreads();
    }
    if (t < NBLK_SCAN) bsums[t] = val - v;
}

__global__ __launch_bounds__(256) void scan3(int* __restrict__ offs,
                                             const int* __restrict__ bsums) {
    int i = blockIdx.x * 256 + threadIdx.x;
    if (i < NN) offs[i] += bsums[i >> 10];
    if (i == 0) offs[NN] = NE;
}

// ---------------- phase 3: bin edges by dst ------------------------------
// cur[] is pre-initialized to offs[] (d2d copy) -> atomicAdd returns the
// slot directly, no separate offs read.
__global__ __launch_bounds__(256) void fill_bins(const int* __restrict__ src,
                                                 const int* __restrict__ dst,
                                                 const int* __restrict__ et,
                                                 int* __restrict__ cur,
                                                 int* __restrict__ ebin) {
    int e = blockIdx.x * 256 + threadIdx.x;
    if (e >= NE) return;
    int idx = atomicAdd(&cur[dst[e]], 1);
    ebin[idx] = (et[e] << 16) | src[e];   // src < 50000 < 2^16
}

// ---------------- prep: x fp32 -> bf16 -----------------------------------
__global__ __launch_bounds__(256) void convert_x(const float* __restrict__ x,
                                                 u16* __restrict__ xb) {
    int i = (blockIdx.x * 256 + threadIdx.x) * 4;
    if (i >= NN * D) return;
    float4 v = *(const float4*)(x + i);
    ushort4 o;
    o.x = f2bf(v.x); o.y = f2bf(v.y); o.z = f2bf(v.z); o.w = f2bf(v.w);
    *(ushort4*)(xb + i) = o;
}

// ---------------- prep: transpose weight/root -> bf16 [n][k] -------------
__global__ __launch_bounds__(256) void transpose_w(const float* __restrict__ weight,
                                                   const float* __restrict__ root,
                                                   u16* __restrict__ wt,
                                                   u16* __restrict__ rt) {
    int gid = blockIdx.x * 256 + threadIdx.x;
    if (gid >= (NR + 1) * D * D) return;
    int p = gid >> 14;            // plane 0..8
    int idx = gid & 16383;        // n*128 + k
    int n = idx >> 7, k = idx & 127;
    float v = (p < NR) ? weight[(size_t)p * D * D + k * D + n] : root[k * D + n];
    u16* dst = (p < NR) ? (wt + (size_t)p * D * D) : rt;
    dst[idx] = f2bf(v);
}

// ---------------- phase 4: per-dst aggregation (pipelined gather) --------
// One 64-lane wave per node, zero LDS. bf16 row gather: 256B/row = one u32
// per lane. Edge decode wave-uniform (readfirstlane -> scalar switch).
// Depth-8 rotating software pipeline: consume oldest slot, refill with
// edge e+8 -> ~8 row-gathers in flight per wave at all times.
__global__ __launch_bounds__(128) void aggregate_kernel(const u32* __restrict__ xw,
                                                        const int* __restrict__ offs,
                                                        const int* __restrict__ ebin,
                                                        u32* __restrict__ sw) {
    const int lane = threadIdx.x & 63;
    const int n = blockIdx.x * 2 + (threadIdx.x >> 6);
    if (n >= NN) return;
    const int beg = __builtin_amdgcn_readfirstlane(offs[n]);
    const int c   = __builtin_amdgcn_readfirstlane(offs[n + 1]) - beg;

    float acc[NR][2];
    int cnt[NR];
#pragma unroll
    for (int r = 0; r < NR; ++r) { acc[r][0] = 0.f; acc[r][1] = 0.f; cnt[r] = 0; }

    int q0 = 0, q1 = 0, q2 = 0, q3 = 0, q4 = 0, q5 = 0, q6 = 0, q7 = 0;
    u32 v0 = 0, v1 = 0, v2 = 0, v3 = 0, v4 = 0, v5 = 0, v6 = 0, v7 = 0;

#define REFILL(Q, V, IDX)                                                   \
    if ((IDX) < c) {                                                        \
        Q = __builtin_amdgcn_readfirstlane(ebin[beg + (IDX)]);              \
        V = xw[(size_t)((u32)Q & 0xffffu) * 64 + lane];                     \
    }
#define CONSUME(Q, V)                                                       \
    {                                                                       \
        float lo_ = __uint_as_float((V) << 16);                             \
        float hi_ = __uint_as_float((V) & 0xffff0000u);                     \
        switch ((u32)(Q) >> 16) {                                           \
        case 0: acc[0][0] += lo_; acc[0][1] += hi_; ++cnt[0]; break;        \
        case 1: acc[1][0] += lo_; acc[1][1] += hi_; ++cnt[1]; break;        \
        case 2: acc[2][0] += lo_; acc[2][1] += hi_; ++cnt[2]; break;        \
        case 3: acc[3][0] += lo_; acc[3][1] += hi_; ++cnt[3]; break;        \
        case 4: acc[4][0] += lo_; acc[4][1] += hi_; ++cnt[4]; break;        \
        case 5: acc[5][0] += lo_; acc[5][1] += hi_; ++cnt[5]; break;        \
        case 6: acc[6][0] += lo_; acc[6][1] += hi_; ++cnt[6]; break;        \
        default: acc[7][0] += lo_; acc[7][1] += hi_; ++cnt[7]; break;       \
        }                                                                   \
    }

    // prologue: prime 8 slots
    REFILL(q0, v0, 0) REFILL(q1, v1, 1) REFILL(q2, v2, 2) REFILL(q3, v3, 3)
    REFILL(q4, v4, 4) REFILL(q5, v5, 5) REFILL(q6, v6, 6) REFILL(q7, v7, 7)

    int e = 0;
    for (; e + 8 <= c; e += 8) {
        CONSUME(q0, v0) REFILL(q0, v0, e + 8)
        CONSUME(q1, v1) REFILL(q1, v1, e + 9)
        CONSUME(q2, v2) REFILL(q2, v2, e + 10)
        CONSUME(q3, v3) REFILL(q3, v3, e + 11)
        CONSUME(q4, v4) REFILL(q4, v4, e + 12)
        CONSUME(q5, v5) REFILL(q5, v5, e + 13)
        CONSUME(q6, v6) REFILL(q6, v6, e + 14)
        CONSUME(q7, v7) REFILL(q7, v7, e + 15)
    }
    // tail: slot i holds edge e+i iff e+i<c
    if (e + 0 < c) CONSUME(q0, v0)
    if (e + 1 < c) CONSUME(q1, v1)
    if (e + 2 < c) CONSUME(q2, v2)
    if (e + 3 < c) CONSUME(q3, v3)
    if (e + 4 < c) CONSUME(q4, v4)
    if (e + 5 < c) CONSUME(q5, v5)
    if (e + 6 < c) CONSUME(q6, v6)
    if (e + 7 < c) CONSUME(q7, v7)
#undef REFILL
#undef CONSUME

#pragma unroll
    for (int r = 0; r < NR; ++r) {
        float inv = 1.0f / (float)(cnt[r] > 0 ? cnt[r] : 1);
        u32 lo16 = f2bf(acc[r][0] * inv);
        u32 hi16 = f2bf(acc[r][1] * inv);
        sw[((size_t)r * NN + n) * 64 + lane] = lo16 | (hi16 << 16);
    }
}

// ---------------- phase 5: fused MFMA GEMM -------------------------------
// out[n][c] = relu( Σ_k A[n][k] * B[k][c] + bias[c] ), K = 1152
// BM=128, BN=128 (full), BK=32; 256 threads = 4 waves, each wave 64x64.
__global__ __launch_bounds__(256) void mfma_gemm(const u16* __restrict__ xb,
                                                 const u16* __restrict__ sums,
                                                 const u16* __restrict__ rt,
                                                 const u16* __restrict__ wt,
                                                 const float* __restrict__ bias,
                                                 float* __restrict__ out) {
    __shared__ u16 As[128 * 32];   // [row][k] rows of 64B
    __shared__ u16 Bs[128 * 32];   // [col][k] rows of 64B

    const int tid  = threadIdx.x;
    const int wave = tid >> 6;
    const int lane = tid & 63;
    const int wm   = (wave & 1) * 64;
    const int wn   = (wave >> 1) * 64;
    const int m0   = blockIdx.x * 128;

    f32x4 acc[4][4];
#pragma unroll
    for (int i = 0; i < 4; ++i)
#pragma unroll
        for (int j = 0; j < 4; ++j) acc[i][j] = (f32x4){0.f, 0.f, 0.f, 0.f};

    for (int k0 = 0; k0 < KT; k0 += 32) {
        const int rpl = k0 >> 7;
        const int kof = k0 & 127;
        const u16* Ap = (rpl == 0) ? xb : sums + (size_t)(rpl - 1) * NN * D;
        const u16* Bp = (rpl == 0) ? rt : wt + (size_t)(rpl - 1) * D * D;

        __syncthreads();
#pragma unroll
        for (int j = 0; j < 2; ++j) {
            int row = wave * 32 + j * 16 + (lane >> 2);
            int ga  = m0 + row; if (ga > NN - 1) ga = NN - 1;   // clamp tail
            async_cp16(Ap + (size_t)ga * D + kof + (lane & 3) * 8,
                       &As[(wave * 32 + j * 16) * 32]);
            async_cp16(Bp + (size_t)row * D + kof + (lane & 3) * 8,
                       &Bs[(wave * 32 + j * 16) * 32]);
        }
        __syncthreads();

        s16x8 af[4], bf[4];
        const int fr = lane & 15;
        const int fk = (lane >> 4) * 8;
#pragma unroll
        for (int mt = 0; mt < 4; ++mt)
            af[mt] = *(const s16x8*)&As[(wm + mt * 16 + fr) * 32 + fk];
#pragma unroll
        for (int nt = 0; nt < 4; ++nt)
            bf[nt] = *(const s16x8*)&Bs[(wn + nt * 16 + fr) * 32 + fk];
#pragma unroll
        for (int mt = 0; mt < 4; ++mt)
#pragma unroll
            for (int nt = 0; nt < 4; ++nt)
                acc[mt][nt] = __builtin_amdgcn_mfma_f32_16x16x32_bf16(
                    af[mt], bf[nt], acc[mt][nt], 0, 0, 0);
    }

    // epilogue: C/D layout col=lane&15, row=(lane>>4)*4+reg
    const int cl = lane & 15;
    const int rq = (lane >> 4) * 4;
#pragma unroll
    for (int nt = 0; nt < 4; ++nt) {
        int col = wn + nt * 16 + cl;
        float bv = bias[col];
#pragma unroll
        for (int mt = 0; mt < 4; ++mt) {
#pragma unroll
            for (int reg = 0; reg < 4; ++reg) {
                int n = m0 + wm + mt * 16 + rq + reg;
                if (n < NN) {
                    float v = acc[mt][nt][reg] + bv;
                    out[(size_t)n * D + col] = fmaxf(v, 0.0f);
                }
            }
        }
    }
}

extern "C" void kernel_launch(void* const* d_in, const int* in_sizes, int n_in,
                              void* d_out, int out_size, void* d_ws, size_t ws_size,
                              hipStream_t stream) {
    const float* x      = (const float*)d_in[0];
    const int*   ei     = (const int*)d_in[1];
    const int*   et     = (const int*)d_in[2];
    const float* weight = (const float*)d_in[3];
    const float* root   = (const float*)d_in[4];
    const float* bias   = (const float*)d_in[5];
    float* out = (float*)d_out;
    const int* srcv = ei;
    const int* dstv = ei + NE;

    // ws layout: [cnt_d NN][cur NN][offs NN+1][bsums 64][ebin NE] ints,
    // then u16: [xb NN*D][sums NR*NN*D][wt NR*D*D][rt D*D]   (~118.5 MB)
    int* cnt_d = (int*)d_ws;
    int* cur   = cnt_d + NN;
    int* offs  = cur + NN;
    int* bsums = offs + NN + 1;
    int* ebin  = bsums + 64;
    size_t fixed_b  = ((char*)(ebin + NE) - (char*)d_ws);
    size_t fixed_al = (fixed_b + 255) & ~(size_t)255;
    u16* xb   = (u16*)((char*)d_ws + fixed_al);
    u16* sums = xb + (size_t)NN * D;
    u16* wt   = sums + (size_t)NR * NN * D;
    u16* rt   = wt + (size_t)NR * D * D;

    hipMemsetAsync(cnt_d, 0, NN * sizeof(int), stream);
    count_dst<<<(NE + 255) / 256, 256, 0, stream>>>(dstv, cnt_d);
    scan1<<<NBLK_SCAN, 256, 0, stream>>>(cnt_d, offs, bsums);
    scan2<<<1, 64, 0, stream>>>(bsums);
    scan3<<<(NN + 255) / 256, 256, 0, stream>>>(offs, bsums);
    hipMemcpyAsync(cur, offs, NN * sizeof(int), hipMemcpyDeviceToDevice, stream);
    fill_bins<<<(NE + 255) / 256, 256, 0, stream>>>(srcv, dstv, et, cur, ebin);

    convert_x<<<(NN * D / 4 + 255) / 256, 256, 0, stream>>>(x, xb);
    transpose_w<<<((NR + 1) * D * D + 255) / 256, 256, 0, stream>>>(weight, root, wt, rt);

    aggregate_kernel<<<(NN + 1) / 2, 128, 0, stream>>>((const u32*)xb, offs, ebin, (u32*)sums);

    mfma_gemm<<<(NN + 127) / 128, 256, 0, stream>>>(xb, sums, rt, wt, bias, out);
}

// Round 8
// 220.010 us; speedup vs baseline: 1.3096x; 1.2130x over previous
//
#include <hip/hip_runtime.h>

constexpr int NN = 50000;   // nodes
constexpr int NE = 600000;  // edges
constexpr int D  = 128;     // features
constexpr int NR = 8;       // relations
constexpr int KT = (NR + 1) * D;     // 1152 total K
constexpr int NSEG = NN * NR;        // 400000 (dst, rel) segments

constexpr int SCAN_ELEMS = 1024;
constexpr int NBLK2 = (NSEG + SCAN_ELEMS - 1) / SCAN_ELEMS;   // 391

typedef unsigned int   u32;
typedef unsigned short u16;
typedef float  f32x4 __attribute__((ext_vector_type(4)));
typedef short  s16x8 __attribute__((ext_vector_type(8)));

__device__ __forceinline__ u16 f2bf(float f) {
    u32 u = __float_as_uint(f);
    u32 r = (u + 0x7fffu + ((u >> 16) & 1u)) >> 16;   // RNE
    return (u16)r;
}

__device__ __forceinline__ void async_cp16(const void* g, void* l) {
    __builtin_amdgcn_global_load_lds(
        (const __attribute__((address_space(1))) u32*)g,
        (__attribute__((address_space(3))) u32*)l, 16, 0, 0);
}

// ---------------- fused prep: count2 + convert_x + transpose_w -----------
__global__ __launch_bounds__(256) void prep_all(const float* __restrict__ x,
                                                const float* __restrict__ weight,
                                                const float* __restrict__ root,
                                                const int* __restrict__ dst,
                                                const int* __restrict__ et,
                                                u16* __restrict__ xb,
                                                u16* __restrict__ wt,
                                                u16* __restrict__ rt,
                                                int* __restrict__ cnt2) {
    const int NX4 = NN * D / 4;                 // 1.6M
    const int NW  = (NR + 1) * D * D;           // 147456
    int gid = blockIdx.x * 256 + threadIdx.x;
    if (gid < NX4) {
        int i = gid * 4;
        float4 v = *(const float4*)(x + i);
        ushort4 o;
        o.x = f2bf(v.x); o.y = f2bf(v.y); o.z = f2bf(v.z); o.w = f2bf(v.w);
        *(ushort4*)(xb + i) = o;
        return;
    }
    int g = gid - NX4;
    if (g < NW) {
        int p = g >> 14;          // plane 0..8
        int idx = g & 16383;      // n*128 + k
        int n = idx >> 7, k = idx & 127;
        float v = (p < NR) ? weight[(size_t)p * D * D + k * D + n] : root[k * D + n];
        u16* dp = (p < NR) ? (wt + (size_t)p * D * D) : rt;
        dp[idx] = f2bf(v);
        return;
    }
    int e = g - NW;
    if (e < NE) atomicAdd(&cnt2[dst[e] * NR + et[e]], 1);
}

// ---------------- scans: exclusive scan of cnt2 -> offs2 -----------------
__global__ __launch_bounds__(256) void scan1(const int* __restrict__ cnt,
                                             int* __restrict__ offs,
                                             int* __restrict__ bsums) {
    __shared__ int lds[256];
    int t = threadIdx.x;
    int base = blockIdx.x * SCAN_ELEMS + t * 4;
    int v0 = (base + 0 < NSEG) ? cnt[base + 0] : 0;
    int v1 = (base + 1 < NSEG) ? cnt[base + 1] : 0;
    int v2 = (base + 2 < NSEG) ? cnt[base + 2] : 0;
    int v3 = (base + 3 < NSEG) ? cnt[base + 3] : 0;
    int s = v0 + v1 + v2 + v3;
    lds[t] = s;
    __syncthreads();
    int val = s;
    for (int off = 1; off < 256; off <<= 1) {
        int tmp = (t >= off) ? lds[t - off] : 0;
        __syncthreads();
        val += tmp;
        lds[t] = val;
        __syncthreads();
    }
    int ex = val - s;
    if (base + 0 < NSEG) offs[base + 0] = ex;
    if (base + 1 < NSEG) offs[base + 1] = ex + v0;
    if (base + 2 < NSEG) offs[base + 2] = ex + v0 + v1;
    if (base + 3 < NSEG) offs[base + 3] = ex + v0 + v1 + v2;
    if (t == 255) bsums[blockIdx.x] = val;
}

__global__ __launch_bounds__(512) void scan2(int* __restrict__ bsums) {
    __shared__ int lds[512];
    int t = threadIdx.x;
    int v = (t < NBLK2) ? bsums[t] : 0;
    lds[t] = v;
    __syncthreads();
    int val = v;
    for (int off = 1; off < 512; off <<= 1) {
        int tmp = (t >= off) ? lds[t - off] : 0;
        __syncthreads();
        val += tmp;
        lds[t] = val;
        __syncthreads();
    }
    if (t < NBLK2) bsums[t] = val - v;
}

// also initializes cur2 (saves the d2d copy) and the sentinel
__global__ __launch_bounds__(256) void scan3(int* __restrict__ offs,
                                             int* __restrict__ cur,
                                             const int* __restrict__ bsums) {
    int i = blockIdx.x * 256 + threadIdx.x;
    if (i < NSEG) {
        int v = offs[i] + bsums[i >> 10];
        offs[i] = v;
        cur[i]  = v;
    }
    if (i == 0) offs[NSEG] = NE;
}

// ---------------- bin edges by (dst, rel) --------------------------------
__global__ __launch_bounds__(256) void fill_bins(const int* __restrict__ src,
                                                 const int* __restrict__ dst,
                                                 const int* __restrict__ et,
                                                 int* __restrict__ cur,
                                                 int* __restrict__ ebin) {
    int e = blockIdx.x * 256 + threadIdx.x;
    if (e >= NE) return;
    int r = et[e];
    int idx = atomicAdd(&cur[dst[e] * NR + r], 1);
    ebin[idx] = (r << 16) | src[e];   // src < 50000 < 2^16
}

// ---------------- aggregation: relation-sorted, boundary-flush -----------
// One 64-lane wave per node, zero LDS. Edges arrive sorted by relation, so
// one running (lo,hi) accumulator pair suffices; a scalar flush at each
// relation boundary writes that relation's mean (zeros for empty segments)
// and the flush counter IS the segment count. Depth-8 gather pipeline.
__global__ __launch_bounds__(128) void aggregate_kernel(const u32* __restrict__ xw,
                                                        const int* __restrict__ offs2,
                                                        const int* __restrict__ ebin,
                                                        u32* __restrict__ sw) {
    const int lane = threadIdx.x & 63;
    const int n = blockIdx.x * 2 + (threadIdx.x >> 6);
    if (n >= NN) return;
    const int beg = __builtin_amdgcn_readfirstlane(offs2[n * NR]);
    const int c   = __builtin_amdgcn_readfirstlane(offs2[n * NR + NR]) - beg;

    float a0 = 0.f, a1 = 0.f;
    int r_cur = 0, cnt_cur = 0;

    int q0 = 0, q1 = 0, q2 = 0, q3 = 0, q4 = 0, q5 = 0, q6 = 0, q7 = 0;
    u32 v0 = 0, v1 = 0, v2 = 0, v3 = 0, v4 = 0, v5 = 0, v6 = 0, v7 = 0;

#define REFILL(Q, V, IDX)                                                   \
    if ((IDX) < c) {                                                        \
        Q = __builtin_amdgcn_readfirstlane(ebin[beg + (IDX)]);              \
        V = xw[(size_t)((u32)Q & 0xffffu) * 64 + lane];                     \
    }
#define FLUSH()                                                             \
    {                                                                       \
        float inv_ = 1.0f / (float)(cnt_cur > 0 ? cnt_cur : 1);             \
        u32 lo16_ = f2bf(a0 * inv_);                                        \
        u32 hi16_ = f2bf(a1 * inv_);                                        \
        sw[((size_t)r_cur * NN + n) * 64 + lane] = lo16_ | (hi16_ << 16);   \
        a0 = 0.f; a1 = 0.f; cnt_cur = 0; ++r_cur;                           \
    }
#define CONSUME(Q, V)                                                       \
    {                                                                       \
        int rj_ = (int)((u32)(Q) >> 16);                                    \
        while (r_cur < rj_) FLUSH()                                         \
        a0 += __uint_as_float((V) << 16);                                   \
        a1 += __uint_as_float((V) & 0xffff0000u);                           \
        ++cnt_cur;                                                          \
    }

    REFILL(q0, v0, 0) REFILL(q1, v1, 1) REFILL(q2, v2, 2) REFILL(q3, v3, 3)
    REFILL(q4, v4, 4) REFILL(q5, v5, 5) REFILL(q6, v6, 6) REFILL(q7, v7, 7)

    int e = 0;
    for (; e + 8 <= c; e += 8) {
        CONSUME(q0, v0) REFILL(q0, v0, e + 8)
        CONSUME(q1, v1) REFILL(q1, v1, e + 9)
        CONSUME(q2, v2) REFILL(q2, v2, e + 10)
        CONSUME(q3, v3) REFILL(q3, v3, e + 11)
        CONSUME(q4, v4) REFILL(q4, v4, e + 12)
        CONSUME(q5, v5) REFILL(q5, v5, e + 13)
        CONSUME(q6, v6) REFILL(q6, v6, e + 14)
        CONSUME(q7, v7) REFILL(q7, v7, e + 15)
    }
    if (e + 0 < c) CONSUME(q0, v0)
    if (e + 1 < c) CONSUME(q1, v1)
    if (e + 2 < c) CONSUME(q2, v2)
    if (e + 3 < c) CONSUME(q3, v3)
    if (e + 4 < c) CONSUME(q4, v4)
    if (e + 5 < c) CONSUME(q5, v5)
    if (e + 6 < c) CONSUME(q6, v6)
    if (e + 7 < c) CONSUME(q7, v7)

    while (r_cur < NR) FLUSH()
#undef REFILL
#undef FLUSH
#undef CONSUME
}

// ---------------- fused MFMA GEMM ----------------------------------------
// out[n][c] = relu( Σ_k A[n][k] * B[k][c] + bias[c] ), K = 1152
// BM=64 (782 blocks -> ~3 blocks/CU for barrier overlap), BN=128, BK=32;
// 4 waves, each 16 rows x 128 cols = 8 MFMA/iter. LDS 12 KB.
__global__ __launch_bounds__(256) void mfma_gemm(const u16* __restrict__ xb,
                                                 const u16* __restrict__ sums,
                                                 const u16* __restrict__ rt,
                                                 const u16* __restrict__ wt,
                                                 const float* __restrict__ bias,
                                                 float* __restrict__ out) {
    __shared__ u16 As[64 * 32];    // [row][k] rows of 64B (4 KB)
    __shared__ u16 Bs[128 * 32];   // [col][k] rows of 64B (8 KB)

    const int tid  = threadIdx.x;
    const int wave = tid >> 6;
    const int lane = tid & 63;
    const int m0   = blockIdx.x * 64;

    f32x4 acc[8];
#pragma unroll
    for (int j = 0; j < 8; ++j) acc[j] = (f32x4){0.f, 0.f, 0.f, 0.f};

    const int srow = 16 * wave + (lane >> 2);   // staging row for this thread
    const int sch  = (lane & 3) * 8;            // k-offset of its 16B chunk

    for (int k0 = 0; k0 < KT; k0 += 32) {
        const int rpl = k0 >> 7;
        const int kof = k0 & 127;
        const u16* Ap = (rpl == 0) ? xb : sums + (size_t)(rpl - 1) * NN * D;
        const u16* Bp = (rpl == 0) ? rt : wt + (size_t)(rpl - 1) * D * D;

        __syncthreads();
        {
            int ga = m0 + srow; if (ga > NN - 1) ga = NN - 1;   // tail clamp
            async_cp16(Ap + (size_t)ga * D + kof + sch, (char*)As + wave * 1024);
            async_cp16(Bp + (size_t)srow * D + kof + sch, (char*)Bs + wave * 1024);
            async_cp16(Bp + (size_t)(64 + srow) * D + kof + sch,
                       (char*)Bs + 4096 + wave * 1024);
        }
        __syncthreads();

        const int fr = lane & 15;
        const int fk = (lane >> 4) * 8;
        s16x8 af = *(const s16x8*)&As[(16 * wave + fr) * 32 + fk];
#pragma unroll
        for (int nt = 0; nt < 8; ++nt) {
            s16x8 bf = *(const s16x8*)&Bs[(nt * 16 + fr) * 32 + fk];
            acc[nt] = __builtin_amdgcn_mfma_f32_16x16x32_bf16(af, bf, acc[nt], 0, 0, 0);
        }
    }

    // epilogue: C/D layout col=lane&15, row=(lane>>4)*4+reg
    const int cl = lane & 15;
    const int rq = (lane >> 4) * 4;
#pragma unroll
    for (int nt = 0; nt < 8; ++nt) {
        int col = nt * 16 + cl;
        float bv = bias[col];
#pragma unroll
        for (int reg = 0; reg < 4; ++reg) {
            int n = m0 + 16 * wave + rq + reg;
            if (n < NN) {
                float v = acc[nt][reg] + bv;
                out[(size_t)n * D + col] = fmaxf(v, 0.0f);
            }
        }
    }
}

extern "C" void kernel_launch(void* const* d_in, const int* in_sizes, int n_in,
                              void* d_out, int out_size, void* d_ws, size_t ws_size,
                              hipStream_t stream) {
    const float* x      = (const float*)d_in[0];
    const int*   ei     = (const int*)d_in[1];
    const int*   et     = (const int*)d_in[2];
    const float* weight = (const float*)d_in[3];
    const float* root   = (const float*)d_in[4];
    const float* bias   = (const float*)d_in[5];
    float* out = (float*)d_out;
    const int* srcv = ei;
    const int* dstv = ei + NE;

    // ws: ints [cnt2 NSEG][cur2 NSEG][offs2 NSEG+1][bsums 512][ebin NE],
    // then u16 [xb NN*D][sums NR*NN*D][wt NR*D*D][rt D*D]   (~118 MB)
    int* cnt2  = (int*)d_ws;
    int* cur2  = cnt2 + NSEG;
    int* offs2 = cur2 + NSEG;
    int* bsums = offs2 + NSEG + 1;
    int* ebin  = bsums + 512;
    size_t fixed_b  = ((char*)(ebin + NE) - (char*)d_ws);
    size_t fixed_al = (fixed_b + 255) & ~(size_t)255;
    u16* xb   = (u16*)((char*)d_ws + fixed_al);
    u16* sums = xb + (size_t)NN * D;
    u16* wt   = sums + (size_t)NR * NN * D;
    u16* rt   = wt + (size_t)NR * D * D;

    hipMemsetAsync(cnt2, 0, NSEG * sizeof(int), stream);

    const int PREP = NN * D / 4 + (NR + 1) * D * D + NE;
    prep_all<<<(PREP + 255) / 256, 256, 0, stream>>>(x, weight, root, dstv, et,
                                                     xb, wt, rt, cnt2);

    scan1<<<NBLK2, 256, 0, stream>>>(cnt2, offs2, bsums);
    scan2<<<1, 512, 0, stream>>>(bsums);
    scan3<<<(NSEG + 256) / 256, 256, 0, stream>>>(offs2, cur2, bsums);
    fill_bins<<<(NE + 255) / 256, 256, 0, stream>>>(srcv, dstv, et, cur2, ebin);

    aggregate_kernel<<<(NN + 1) / 2, 128, 0, stream>>>((const u32*)xb, offs2, ebin,
                                                       (u32*)sums);

    mfma_gemm<<<(NN + 63) / 64, 256, 0, stream>>>(xb, sums, rt, wt, bias, out);
}